// Round 1
// baseline (132.460 us; speedup 1.0000x reference)
//
#include <hip/hip_runtime.h>
#include <stdint.h>

#define N_NODES 20000
#define N_EDGES 240000
#define IN_DIM  20
#define OUT_DIM 360   // 20 mlp + 20 sender-sum + 320 tp
#define EPS_F   1e-12f
#define CAP     64    // bucket capacity per node (Binomial mean 12, max ~35)
#define EDGE_BLOCKS ((N_EDGES + 255) / 256)   // 938
#define MLP_BLOCKS  ((N_NODES + 255) / 256)   // 79

typedef _Float16 half8   __attribute__((ext_vector_type(8)));
typedef float    floatx16 __attribute__((ext_vector_type(16)));
typedef uint32_t uint4v  __attribute__((ext_vector_type(4)));

__device__ __forceinline__ uint32_t pack_h2(float a, float b) {
    union { _Float16 f[2]; uint32_t u; } t;
    t.f[0] = (_Float16)a; t.f[1] = (_Float16)b;   // RNE converts
    return t.u;
}

__device__ __forceinline__ half8 h8_from_u32(uint32_t u0, uint32_t u1,
                                             uint32_t u2, uint32_t u3) {
    union { uint32_t u[4]; half8 h; } t;
    t.u[0] = u0; t.u[1] = u1; t.u[2] = u2; t.u[3] = u3;
    return t.h;
}

// tail-mask for B fragment: halves j, j+1 valid iff j < t
__device__ __forceinline__ uint32_t maskpair(int t, int j) {
    return (t > j ? 0xFFFFu : 0u) | (t > j + 1 ? 0xFFFF0000u : 0u);
}

// used only in the (normally never-taken) overflow path
__device__ __forceinline__ float sh_coeff(int k, float xn, float yn, float zn) {
    const float x2 = xn * xn, y2 = yn * yn, z2 = zn * zn;
    switch (k) {
        case 0:  return 0.28209479177387814f;
        case 1:  return 0.4886025119029199f * yn;
        case 2:  return 0.4886025119029199f * zn;
        case 3:  return 0.4886025119029199f * xn;
        case 4:  return 1.0925484305920792f * xn * yn;
        case 5:  return 1.0925484305920792f * yn * zn;
        case 6:  return 0.31539156525252005f * (3.0f * z2 - 1.0f);
        case 7:  return 1.0925484305920792f * xn * zn;
        case 8:  return 0.5462742152960396f * (x2 - y2);
        case 9:  return 0.5900435899266435f * yn * (3.0f * x2 - y2);
        case 10: return 2.890611442640554f  * xn * yn * zn;
        case 11: return 0.4570457994644658f * yn * (5.0f * z2 - 1.0f);
        case 12: return 0.3731763325901154f * zn * (5.0f * z2 - 3.0f);
        case 13: return 0.4570457994644658f * xn * (5.0f * z2 - 1.0f);
        case 14: return 1.445305721320277f  * zn * (x2 - y2);
        default: return 0.5900435899266435f * xn * (x2 - 3.0f * y2); // k==15
    }
}

// ------- fused: bucket build + per-edge SH (thread/edge)  ||  node MLP (thread/node) -------
// shB layout (B-fragment friendly): u32 shB[node][b(4)][cp(8)][kk(16)]
//   where cp = comp>>1, u32 = {f16 sh[2cp] (lo), f16 sh[2cp+1] (hi)}, kk = slot&15.
// xpair: u32 xpair[node][20] = {f16 hi(x) (lo), f16 residual (hi)} — compensated pair.
__global__ __launch_bounds__(256) void bucket_sh_mlp(
    const float* __restrict__ pos,
    const int* __restrict__ ei,
    const float* __restrict__ x,
    const float* __restrict__ Wpre,  const float* __restrict__ bpre,
    const float* __restrict__ Wpost, const float* __restrict__ bpost,
    const float* __restrict__ Wsc,   const float* __restrict__ bsc,
    int* __restrict__ counts,      // [N_NODES]
    int* __restrict__ ovf_cnt,     // [1]
    int* __restrict__ ovf,         // [N_EDGES] (exact)
    int* __restrict__ bucket,      // [N_NODES * CAP] holds ROW
    uint32_t* __restrict__ shB,    // [N_NODES*4*8*16]
    uint32_t* __restrict__ xpair,  // [N_NODES*IN_DIM]
    float* __restrict__ out)
{
    if ((int)blockIdx.x < EDGE_BLOCKS) {
        // ---------------- edge part ----------------
        const int e = (int)(blockIdx.x * 256 + threadIdx.x);
        if (e >= N_EDGES) return;
        const int row = ei[e];
        const int col = ei[N_EDGES + e];
        const int slot = atomicAdd(&counts[col], 1);
        if (slot >= CAP) { ovf[atomicAdd(ovf_cnt, 1)] = e; return; }

        bucket[col * CAP + slot] = row;

        const float rx = pos[col * 3 + 0] - pos[row * 3 + 0];
        const float ry = pos[col * 3 + 1] - pos[row * 3 + 1];
        const float rz = pos[col * 3 + 2] - pos[row * 3 + 2];
        const float rinv = rsqrtf(rx * rx + ry * ry + rz * rz + EPS_F);
        const float xx = rx * rinv, yy = ry * rinv, zz = rz * rinv;
        const float x2 = xx * xx, y2 = yy * yy, z2 = zz * zz;

        const float sh0  = 0.28209479177387814f;
        const float sh1  = 0.4886025119029199f * yy;
        const float sh2  = 0.4886025119029199f * zz;
        const float sh3  = 0.4886025119029199f * xx;
        const float sh4  = 1.0925484305920792f * xx * yy;
        const float sh5  = 1.0925484305920792f * yy * zz;
        const float sh6  = 0.31539156525252005f * (3.0f * z2 - 1.0f);
        const float sh7  = 1.0925484305920792f * xx * zz;
        const float sh8  = 0.5462742152960396f * (x2 - y2);
        const float sh9  = 0.5900435899266435f * yy * (3.0f * x2 - y2);
        const float sh10 = 2.890611442640554f  * xx * yy * zz;
        const float sh11 = 0.4570457994644658f * yy * (5.0f * z2 - 1.0f);
        const float sh12 = 0.3731763325901154f * zz * (5.0f * z2 - 3.0f);
        const float sh13 = 0.4570457994644658f * xx * (5.0f * z2 - 1.0f);
        const float sh14 = 1.445305721320277f  * zz * (x2 - y2);
        const float sh15 = 0.5900435899266435f * xx * (x2 - 3.0f * y2);

        const int bb = slot >> 4, kk = slot & 15;
        uint32_t* dst = shB + (size_t)(col * 4 + bb) * 128 + kk;   // cp stride = 16 u32
        dst[0 * 16] = pack_h2(sh0,  sh1);
        dst[1 * 16] = pack_h2(sh2,  sh3);
        dst[2 * 16] = pack_h2(sh4,  sh5);
        dst[3 * 16] = pack_h2(sh6,  sh7);
        dst[4 * 16] = pack_h2(sh8,  sh9);
        dst[5 * 16] = pack_h2(sh10, sh11);
        dst[6 * 16] = pack_h2(sh12, sh13);
        dst[7 * 16] = pack_h2(sh14, sh15);
        return;
    }

    // ---------------- MLP part: thread per node ----------------
    __shared__ float sWpre[IN_DIM * IN_DIM];
    __shared__ float sWpost[IN_DIM * IN_DIM];
    __shared__ float sWsc[IN_DIM * IN_DIM];
    __shared__ float sb[3 * IN_DIM];

    for (int t = threadIdx.x; t < IN_DIM * IN_DIM; t += 256) {
        sWpre[t]  = Wpre[t];
        sWpost[t] = Wpost[t];
        sWsc[t]   = Wsc[t];
    }
    if (threadIdx.x < IN_DIM) {
        sb[threadIdx.x]              = bpre[threadIdx.x];
        sb[IN_DIM + threadIdx.x]     = bpost[threadIdx.x];
        sb[2 * IN_DIM + threadIdx.x] = bsc[threadIdx.x];
    }
    __syncthreads();

    const int i = (int)((blockIdx.x - EDGE_BLOCKS) * 256 + threadIdx.x);
    if (i >= N_NODES) return;

    float xi[IN_DIM], h[IN_DIM];
#pragma unroll
    for (int j = 0; j < IN_DIM; ++j) xi[j] = x[(size_t)i * IN_DIM + j];

    // compensated f16 pair for the gather kernel's MFMA A-operand
#pragma unroll
    for (int j = 0; j < IN_DIM; ++j) {
        const float v = xi[j];
        const _Float16 hh = (_Float16)v;
        const float res = v - (float)hh;
        union { _Float16 f[2]; uint32_t u; } t;
        t.f[0] = hh; t.f[1] = (_Float16)res;
        xpair[(size_t)i * IN_DIM + j] = t.u;
    }

#pragma unroll
    for (int j = 0; j < IN_DIM; ++j) {
        float a = sb[j];
#pragma unroll
        for (int kk = 0; kk < IN_DIM; ++kk) a = fmaf(xi[kk], sWpre[j * IN_DIM + kk], a);
        h[j] = fmaxf(a, 0.0f);
    }
#pragma unroll
    for (int j = 0; j < IN_DIM; ++j) {
        float a = sb[IN_DIM + j] + sb[2 * IN_DIM + j];
#pragma unroll
        for (int kk = 0; kk < IN_DIM; ++kk) {
            a = fmaf(h[kk],  sWpost[j * IN_DIM + kk], a);
            a = fmaf(xi[kk], sWsc[j * IN_DIM + kk],  a);
        }
        out[(size_t)i * OUT_DIM + j] = a;
    }
}

// -------- gather: one wave per node, 16-edge blocks via v_mfma_f32_32x32x16_f16 --------
// C[row=feature i][col=sh comp k] = sum_e s_e[i]*sh_e[k]; col 16 = ones => sender sums.
// A: lane row = lane&31, k = 8*(lane>>5)+j. B: lane col = lane&31, same k. (C/D layout
// per guide m74/m101: col=lane&31, row=(reg&3)+8*(reg>>2)+4*(lane>>5).)
__global__ __launch_bounds__(256) void node_gather(
    const float* __restrict__ x,
    const float* __restrict__ pos,
    const int* __restrict__ ei,
    const int* __restrict__ counts,
    const int* __restrict__ bucket,
    const uint32_t* __restrict__ shB,
    const uint32_t* __restrict__ xpair,
    const int* __restrict__ ovf_cnt,
    const int* __restrict__ ovf,
    float* __restrict__ out)
{
    const int lane  = threadIdx.x & 63;
    const int node  = (int)((blockIdx.x * blockDim.x + threadIdx.x) >> 6); // grid exact
    const int col   = lane & 31;
    const int hi    = lane >> 5;
    const int khalf = hi * 8;
    const int rowc  = min(col, IN_DIM - 1);

    const int cnt_raw = __builtin_amdgcn_readfirstlane(counts[node]);
    const int cnt = min(cnt_raw, CAP);

    floatx16 acc = {0,0,0,0,0,0,0,0,0,0,0,0,0,0,0,0};

    if (cnt > 0) {
        // unclamped preload; garbage slots neutralized by B-mask + index clamp
        const int rl = bucket[node * CAP + lane];
        const int nb = (cnt + 15) >> 4;
        const uint32_t sel = (col & 1) ? 0x07060302u : 0x05040100u;

        for (int b = 0; b < nb; ++b) {
            const int sbase = 16 * b + khalf;

            int rr[8];
#pragma unroll
            for (int j = 0; j < 8; ++j) {
                int r = __shfl(rl, sbase + j, 64);
                rr[j] = (int)min((uint32_t)r, (uint32_t)(N_NODES - 1)); // poison-safe
            }
            uint32_t ee[8];
#pragma unroll
            for (int j = 0; j < 8; ++j)
                ee[j] = xpair[(size_t)rr[j] * IN_DIM + rowc];

            // A fragments: hi halves -> A1, residual halves -> A2
            uint32_t a1u[4], a2u[4];
#pragma unroll
            for (int p = 0; p < 4; ++p) {
                a1u[p] = (ee[2 * p] & 0xFFFFu)  | (ee[2 * p + 1] << 16);
                a2u[p] = (ee[2 * p] >> 16)      | (ee[2 * p + 1] & 0xFFFF0000u);
            }

            // B fragment
            uint32_t B0, B1, B2, B3;
            if (col < 16) {
                const uint32_t* bp = shB + ((size_t)(node * 4 + b) * 8 + (col >> 1)) * 16 + khalf;
                const uint4v lo = *(const uint4v*)bp;
                const uint4v hi4 = *(const uint4v*)(bp + 4);
                B0 = __builtin_amdgcn_perm(lo[1],  lo[0],  sel);
                B1 = __builtin_amdgcn_perm(lo[3],  lo[2],  sel);
                B2 = __builtin_amdgcn_perm(hi4[1], hi4[0], sel);
                B3 = __builtin_amdgcn_perm(hi4[3], hi4[2], sel);
            } else if (col == 16) {          // ones column -> sender sums
                B0 = B1 = B2 = B3 = 0x3C003C00u;
            } else {
                B0 = B1 = B2 = B3 = 0u;
            }
            const int rem = cnt - 16 * b;
            if (rem < 16) {                  // zero invalid edges (incl. poison)
                const int t = rem - khalf;
                B0 &= maskpair(t, 0);
                B1 &= maskpair(t, 2);
                B2 &= maskpair(t, 4);
                B3 &= maskpair(t, 6);
            }

            const half8 hb  = h8_from_u32(B0, B1, B2, B3);
            const half8 ha1 = h8_from_u32(a1u[0], a1u[1], a1u[2], a1u[3]);
            const half8 ha2 = h8_from_u32(a2u[0], a2u[1], a2u[2], a2u[3]);
            acc = __builtin_amdgcn_mfma_f32_32x32x16_f16(ha1, hb, acc, 0, 0, 0);
            acc = __builtin_amdgcn_mfma_f32_32x32x16_f16(ha2, hb, acc, 0, 0, 0);
        }
    }

    // exact overflow fallback (cnt_raw > CAP unreachable for this distribution)
    if (cnt_raw > CAP) {
        const int m = *ovf_cnt;
        for (int t2 = 0; t2 < m; ++t2) {
            const int e = ovf[t2];
            if (ei[N_EDGES + e] != node) continue;   // wave-uniform
            const int row = ei[e];
            const float rx = pos[node * 3 + 0] - pos[row * 3 + 0];
            const float ry = pos[node * 3 + 1] - pos[row * 3 + 1];
            const float rz = pos[node * 3 + 2] - pos[row * 3 + 2];
            const float rinv = rsqrtf(rx * rx + ry * ry + rz * rz + EPS_F);
            float shc;
            if (col < 16)      shc = sh_coeff(col, rx * rinv, ry * rinv, rz * rinv);
            else if (col == 16) shc = 1.0f;
            else                shc = 0.0f;
#pragma unroll
            for (int r = 0; r < 16; ++r) {
                const int rw = ((r & 3) + 8 * (r >> 2)) + 4 * hi;
                if (rw < IN_DIM)
                    acc[r] = fmaf(x[(size_t)row * IN_DIM + rw], shc, acc[r]);
            }
        }
    }

    // epilogue: C -> out (also writes zeros for cnt==0 nodes)
    float* orow = out + (size_t)node * OUT_DIM;
    if (col < 16) {
#pragma unroll
        for (int r = 0; r < 16; ++r) {
            const int rw = ((r & 3) + 8 * (r >> 2)) + 4 * hi;
            if (rw < IN_DIM) orow[2 * IN_DIM + rw * 16 + col] = acc[r];  // tp block
        }
    } else if (col == 16) {
#pragma unroll
        for (int r = 0; r < 16; ++r) {
            const int rw = ((r & 3) + 8 * (r >> 2)) + 4 * hi;
            if (rw < IN_DIM) orow[IN_DIM + rw] = acc[r];                 // sender sums
        }
    }
}

extern "C" void kernel_launch(void* const* d_in, const int* in_sizes, int n_in,
                              void* d_out, int out_size, void* d_ws, size_t ws_size,
                              hipStream_t stream)
{
    const float* x     = (const float*)d_in[0];
    const float* pos   = (const float*)d_in[1];
    const int*   ei    = (const int*)d_in[2];
    const float* Wpre  = (const float*)d_in[3];
    const float* bpre  = (const float*)d_in[4];
    const float* Wpost = (const float*)d_in[5];
    const float* bpost = (const float*)d_in[6];
    const float* Wsc   = (const float*)d_in[7];
    const float* bsc   = (const float*)d_in[8];
    float* out = (float*)d_out;

    // ws layout: [shB: N*4*8*16 u32 = 41MB][xpair: N*20 u32][counts: N][ovf_cnt: 1]
    //            [ovf: E][bucket: N*CAP]
    uint32_t* shB   = (uint32_t*)d_ws;
    uint32_t* xpair = shB + (size_t)N_NODES * 4 * 8 * 16;
    int* ws_i    = (int*)(xpair + (size_t)N_NODES * IN_DIM);
    int* counts  = ws_i;
    int* ovf_cnt = ws_i + N_NODES;
    int* ovf     = ws_i + N_NODES + 1;
    int* bucket  = ws_i + N_NODES + 1 + N_EDGES;

    hipMemsetAsync(counts, 0, (size_t)(N_NODES + 1) * sizeof(int), stream); // counts + ovf_cnt

    bucket_sh_mlp<<<EDGE_BLOCKS + MLP_BLOCKS, 256, 0, stream>>>(
        pos, ei, x, Wpre, bpre, Wpost, bpost, Wsc, bsc,
        counts, ovf_cnt, ovf, bucket, shB, xpair, out);

    node_gather<<<(N_NODES * 64) / 256, 256, 0, stream>>>(   // exactly 5000 blocks
        x, pos, ei, counts, bucket, shB, xpair, ovf_cnt, ovf, out);
}

// Round 2
// 118.638 us; speedup vs baseline: 1.1165x; 1.1165x over previous
//
#include <hip/hip_runtime.h>
#include <stdint.h>

#define N_NODES 20000
#define N_EDGES 240000
#define IN_DIM  20
#define OUT_DIM 360   // 20 mlp + 20 sender-sum + 320 tp
#define EPS_F   1e-12f
#define CAP     64    // bucket capacity per node (Binomial mean 12, max ~35)
#define EDGE_BLOCKS ((N_EDGES + 255) / 256)   // 938
#define MLP_BLOCKS  ((N_NODES + 255) / 256)   // 79

typedef _Float16 half8   __attribute__((ext_vector_type(8)));
typedef float    floatx16 __attribute__((ext_vector_type(16)));

__device__ __forceinline__ half8 h8_from_u32(uint32_t u0, uint32_t u1,
                                             uint32_t u2, uint32_t u3) {
    union { uint32_t u[4]; half8 h; } t;
    t.u[0] = u0; t.u[1] = u1; t.u[2] = u2; t.u[3] = u3;
    return t.h;
}

// tail-mask for B fragment: halves j, j+1 valid iff j < t
__device__ __forceinline__ uint32_t maskpair(int t, int j) {
    return (t > j ? 0xFFFFu : 0u) | (t > j + 1 ? 0xFFFF0000u : 0u);
}

// used only in the (normally never-taken) overflow path
__device__ __forceinline__ float sh_coeff(int k, float xn, float yn, float zn) {
    const float x2 = xn * xn, y2 = yn * yn, z2 = zn * zn;
    switch (k) {
        case 0:  return 0.28209479177387814f;
        case 1:  return 0.4886025119029199f * yn;
        case 2:  return 0.4886025119029199f * zn;
        case 3:  return 0.4886025119029199f * xn;
        case 4:  return 1.0925484305920792f * xn * yn;
        case 5:  return 1.0925484305920792f * yn * zn;
        case 6:  return 0.31539156525252005f * (3.0f * z2 - 1.0f);
        case 7:  return 1.0925484305920792f * xn * zn;
        case 8:  return 0.5462742152960396f * (x2 - y2);
        case 9:  return 0.5900435899266435f * yn * (3.0f * x2 - y2);
        case 10: return 2.890611442640554f  * xn * yn * zn;
        case 11: return 0.4570457994644658f * yn * (5.0f * z2 - 1.0f);
        case 12: return 0.3731763325901154f * zn * (5.0f * z2 - 3.0f);
        case 13: return 0.4570457994644658f * xn * (5.0f * z2 - 1.0f);
        case 14: return 1.445305721320277f  * zn * (x2 - y2);
        default: return 0.5900435899266435f * xn * (x2 - 3.0f * y2); // k==15
    }
}

// ------- fused: bucket build + per-edge SH (thread/edge)  ||  node MLP (thread/node) -------
// shbuf: f16 shbuf[node*CAP + slot][16], PLAIN comp order, 32B contiguous per slot
// (write-side coalescing: 2x16B stores per edge; the transpose happens on the read
//  side in node_gather via ushort gathers within the node's 512B slot block).
// xpair: u32 xpair[node][20] = {f16 hi(x) (lo), f16 residual (hi)} — compensated pair.
__global__ __launch_bounds__(256) void bucket_sh_mlp(
    const float* __restrict__ pos,
    const int* __restrict__ ei,
    const float* __restrict__ x,
    const float* __restrict__ Wpre,  const float* __restrict__ bpre,
    const float* __restrict__ Wpost, const float* __restrict__ bpost,
    const float* __restrict__ Wsc,   const float* __restrict__ bsc,
    int* __restrict__ counts,      // [N_NODES]
    int* __restrict__ ovf_cnt,     // [1]
    int* __restrict__ ovf,         // [N_EDGES] (exact)
    int* __restrict__ bucket,      // [N_NODES * CAP] holds ROW
    half8* __restrict__ shbuf,     // [N_NODES * CAP * 2]
    uint32_t* __restrict__ xpair,  // [N_NODES*IN_DIM]
    float* __restrict__ out)
{
    if ((int)blockIdx.x < EDGE_BLOCKS) {
        // ---------------- edge part ----------------
        const int e = (int)(blockIdx.x * 256 + threadIdx.x);
        if (e >= N_EDGES) return;
        const int row = ei[e];
        const int col = ei[N_EDGES + e];
        const int slot = atomicAdd(&counts[col], 1);
        if (slot >= CAP) { ovf[atomicAdd(ovf_cnt, 1)] = e; return; }

        const int sidx = col * CAP + slot;
        bucket[sidx] = row;

        const float rx = pos[col * 3 + 0] - pos[row * 3 + 0];
        const float ry = pos[col * 3 + 1] - pos[row * 3 + 1];
        const float rz = pos[col * 3 + 2] - pos[row * 3 + 2];
        const float rinv = rsqrtf(rx * rx + ry * ry + rz * rz + EPS_F);
        const float xx = rx * rinv, yy = ry * rinv, zz = rz * rinv;
        const float x2 = xx * xx, y2 = yy * yy, z2 = zz * zz;

        const float sh0  = 0.28209479177387814f;
        const float sh1  = 0.4886025119029199f * yy;
        const float sh2  = 0.4886025119029199f * zz;
        const float sh3  = 0.4886025119029199f * xx;
        const float sh4  = 1.0925484305920792f * xx * yy;
        const float sh5  = 1.0925484305920792f * yy * zz;
        const float sh6  = 0.31539156525252005f * (3.0f * z2 - 1.0f);
        const float sh7  = 1.0925484305920792f * xx * zz;
        const float sh8  = 0.5462742152960396f * (x2 - y2);
        const float sh9  = 0.5900435899266435f * yy * (3.0f * x2 - y2);
        const float sh10 = 2.890611442640554f  * xx * yy * zz;
        const float sh11 = 0.4570457994644658f * yy * (5.0f * z2 - 1.0f);
        const float sh12 = 0.3731763325901154f * zz * (5.0f * z2 - 3.0f);
        const float sh13 = 0.4570457994644658f * xx * (5.0f * z2 - 1.0f);
        const float sh14 = 1.445305721320277f  * zz * (x2 - y2);
        const float sh15 = 0.5900435899266435f * xx * (x2 - 3.0f * y2);

        const half8 v0 = { (_Float16)sh0,  (_Float16)sh1,  (_Float16)sh2,  (_Float16)sh3,
                           (_Float16)sh4,  (_Float16)sh5,  (_Float16)sh6,  (_Float16)sh7 };
        const half8 v1 = { (_Float16)sh8,  (_Float16)sh9,  (_Float16)sh10, (_Float16)sh11,
                           (_Float16)sh12, (_Float16)sh13, (_Float16)sh14, (_Float16)sh15 };
        half8* dst = shbuf + (size_t)sidx * 2;   // 32B per slot, contiguous
        dst[0] = v0;
        dst[1] = v1;
        return;
    }

    // ---------------- MLP part: thread per node ----------------
    __shared__ float sWpre[IN_DIM * IN_DIM];
    __shared__ float sWpost[IN_DIM * IN_DIM];
    __shared__ float sWsc[IN_DIM * IN_DIM];
    __shared__ float sb[3 * IN_DIM];

    for (int t = threadIdx.x; t < IN_DIM * IN_DIM; t += 256) {
        sWpre[t]  = Wpre[t];
        sWpost[t] = Wpost[t];
        sWsc[t]   = Wsc[t];
    }
    if (threadIdx.x < IN_DIM) {
        sb[threadIdx.x]              = bpre[threadIdx.x];
        sb[IN_DIM + threadIdx.x]     = bpost[threadIdx.x];
        sb[2 * IN_DIM + threadIdx.x] = bsc[threadIdx.x];
    }
    __syncthreads();

    const int i = (int)((blockIdx.x - EDGE_BLOCKS) * 256 + threadIdx.x);
    if (i >= N_NODES) return;

    float xi[IN_DIM], h[IN_DIM];
#pragma unroll
    for (int j = 0; j < IN_DIM; ++j) xi[j] = x[(size_t)i * IN_DIM + j];

    // compensated f16 pair for the gather kernel's MFMA A-operand
#pragma unroll
    for (int j = 0; j < IN_DIM; ++j) {
        const float v = xi[j];
        const _Float16 hh = (_Float16)v;
        const float res = v - (float)hh;
        union { _Float16 f[2]; uint32_t u; } t;
        t.f[0] = hh; t.f[1] = (_Float16)res;
        xpair[(size_t)i * IN_DIM + j] = t.u;
    }

#pragma unroll
    for (int j = 0; j < IN_DIM; ++j) {
        float a = sb[j];
#pragma unroll
        for (int kk = 0; kk < IN_DIM; ++kk) a = fmaf(xi[kk], sWpre[j * IN_DIM + kk], a);
        h[j] = fmaxf(a, 0.0f);
    }
#pragma unroll
    for (int j = 0; j < IN_DIM; ++j) {
        float a = sb[IN_DIM + j] + sb[2 * IN_DIM + j];
#pragma unroll
        for (int kk = 0; kk < IN_DIM; ++kk) {
            a = fmaf(h[kk],  sWpost[j * IN_DIM + kk], a);
            a = fmaf(xi[kk], sWsc[j * IN_DIM + kk],  a);
        }
        out[(size_t)i * OUT_DIM + j] = a;
    }
}

// -------- gather: one wave per node, 16-edge blocks via v_mfma_f32_32x32x16_f16 --------
// C[row=feature i][col=sh comp k] = sum_e s_e[i]*sh_e[k]; col 16 = ones => sender sums.
// A: lane row = lane&31, k = 8*(lane>>5)+j (per-lane gather from xpair).
// B: lane col = lane&31; lane c<16 reads comp c of 8 slots via ushort gathers within
//    the node's 512B slot block (L1/L2 resident), packed into 4 u32 k-pairs.
// C/D layout per guide m74/m101: col=lane&31, row=(reg&3)+8*(reg>>2)+4*(lane>>5).
__global__ __launch_bounds__(256) void node_gather(
    const float* __restrict__ x,
    const float* __restrict__ pos,
    const int* __restrict__ ei,
    const int* __restrict__ counts,
    const int* __restrict__ bucket,
    const _Float16* __restrict__ shbuf,
    const uint32_t* __restrict__ xpair,
    const int* __restrict__ ovf_cnt,
    const int* __restrict__ ovf,
    float* __restrict__ out)
{
    const int lane  = threadIdx.x & 63;
    const int node  = (int)((blockIdx.x * blockDim.x + threadIdx.x) >> 6); // grid exact
    const int col   = lane & 31;
    const int hi    = lane >> 5;
    const int khalf = hi * 8;
    const int rowc  = min(col, IN_DIM - 1);

    const int cnt_raw = __builtin_amdgcn_readfirstlane(counts[node]);
    const int cnt = min(cnt_raw, CAP);

    floatx16 acc = {0,0,0,0,0,0,0,0,0,0,0,0,0,0,0,0};

    if (cnt > 0) {
        // unclamped preload; garbage slots neutralized by B-mask + index clamp
        const int rl = bucket[node * CAP + lane];
        const int nb = (cnt + 15) >> 4;

        for (int b = 0; b < nb; ++b) {
            const int sbase = 16 * b + khalf;

            int rr[8];
#pragma unroll
            for (int j = 0; j < 8; ++j) {
                int r = __shfl(rl, sbase + j, 64);
                rr[j] = (int)min((uint32_t)r, (uint32_t)(N_NODES - 1)); // poison-safe
            }
            uint32_t ee[8];
#pragma unroll
            for (int j = 0; j < 8; ++j)
                ee[j] = xpair[(size_t)rr[j] * IN_DIM + rowc];

            // A fragments: hi halves -> A1, residual halves -> A2
            uint32_t a1u[4], a2u[4];
#pragma unroll
            for (int p = 0; p < 4; ++p) {
                a1u[p] = (ee[2 * p] & 0xFFFFu)  | (ee[2 * p + 1] << 16);
                a2u[p] = (ee[2 * p] >> 16)      | (ee[2 * p + 1] & 0xFFFF0000u);
            }

            // B fragment: transpose-on-read (8 ushort gathers in a 512B block)
            uint32_t B0, B1, B2, B3;
            if (col < 16) {
                const uint16_t* bp = (const uint16_t*)shbuf
                                   + (size_t)(node * CAP + sbase) * 16 + col;
                const uint32_t h0 = bp[0 * 16];
                const uint32_t h1 = bp[1 * 16];
                const uint32_t h2 = bp[2 * 16];
                const uint32_t h3 = bp[3 * 16];
                const uint32_t h4 = bp[4 * 16];
                const uint32_t h5 = bp[5 * 16];
                const uint32_t h6 = bp[6 * 16];
                const uint32_t h7 = bp[7 * 16];
                B0 = h0 | (h1 << 16);
                B1 = h2 | (h3 << 16);
                B2 = h4 | (h5 << 16);
                B3 = h6 | (h7 << 16);
            } else if (col == 16) {          // ones column -> sender sums
                B0 = B1 = B2 = B3 = 0x3C003C00u;
            } else {
                B0 = B1 = B2 = B3 = 0u;
            }
            const int rem = cnt - 16 * b;
            if (rem < 16) {                  // zero invalid edges (incl. poison)
                const int t = rem - khalf;
                B0 &= maskpair(t, 0);
                B1 &= maskpair(t, 2);
                B2 &= maskpair(t, 4);
                B3 &= maskpair(t, 6);
            }

            const half8 hb  = h8_from_u32(B0, B1, B2, B3);
            const half8 ha1 = h8_from_u32(a1u[0], a1u[1], a1u[2], a1u[3]);
            const half8 ha2 = h8_from_u32(a2u[0], a2u[1], a2u[2], a2u[3]);
            acc = __builtin_amdgcn_mfma_f32_32x32x16_f16(ha1, hb, acc, 0, 0, 0);
            acc = __builtin_amdgcn_mfma_f32_32x32x16_f16(ha2, hb, acc, 0, 0, 0);
        }
    }

    // exact overflow fallback (cnt_raw > CAP unreachable for this distribution)
    if (cnt_raw > CAP) {
        const int m = *ovf_cnt;
        for (int t2 = 0; t2 < m; ++t2) {
            const int e = ovf[t2];
            if (ei[N_EDGES + e] != node) continue;   // wave-uniform
            const int row = ei[e];
            const float rx = pos[node * 3 + 0] - pos[row * 3 + 0];
            const float ry = pos[node * 3 + 1] - pos[row * 3 + 1];
            const float rz = pos[node * 3 + 2] - pos[row * 3 + 2];
            const float rinv = rsqrtf(rx * rx + ry * ry + rz * rz + EPS_F);
            float shc;
            if (col < 16)       shc = sh_coeff(col, rx * rinv, ry * rinv, rz * rinv);
            else if (col == 16) shc = 1.0f;
            else                shc = 0.0f;
#pragma unroll
            for (int r = 0; r < 16; ++r) {
                const int rw = ((r & 3) + 8 * (r >> 2)) + 4 * hi;
                if (rw < IN_DIM)
                    acc[r] = fmaf(x[(size_t)row * IN_DIM + rw], shc, acc[r]);
            }
        }
    }

    // epilogue: C -> out (also writes zeros for cnt==0 nodes)
    float* orow = out + (size_t)node * OUT_DIM;
    if (col < 16) {
#pragma unroll
        for (int r = 0; r < 16; ++r) {
            const int rw = ((r & 3) + 8 * (r >> 2)) + 4 * hi;
            if (rw < IN_DIM) orow[2 * IN_DIM + rw * 16 + col] = acc[r];  // tp block
        }
    } else if (col == 16) {
#pragma unroll
        for (int r = 0; r < 16; ++r) {
            const int rw = ((r & 3) + 8 * (r >> 2)) + 4 * hi;
            if (rw < IN_DIM) orow[IN_DIM + rw] = acc[r];                 // sender sums
        }
    }
}

extern "C" void kernel_launch(void* const* d_in, const int* in_sizes, int n_in,
                              void* d_out, int out_size, void* d_ws, size_t ws_size,
                              hipStream_t stream)
{
    const float* x     = (const float*)d_in[0];
    const float* pos   = (const float*)d_in[1];
    const int*   ei    = (const int*)d_in[2];
    const float* Wpre  = (const float*)d_in[3];
    const float* bpre  = (const float*)d_in[4];
    const float* Wpost = (const float*)d_in[5];
    const float* bpost = (const float*)d_in[6];
    const float* Wsc   = (const float*)d_in[7];
    const float* bsc   = (const float*)d_in[8];
    float* out = (float*)d_out;

    // ws layout: [shbuf: N*CAP*16 f16 = 41MB][xpair: N*20 u32][counts: N][ovf_cnt: 1]
    //            [ovf: E][bucket: N*CAP]
    half8* shbuf    = (half8*)d_ws;                     // N_NODES*CAP*2 half8s
    uint32_t* xpair = (uint32_t*)((char*)d_ws
                    + (size_t)N_NODES * CAP * 16 * sizeof(_Float16));
    int* ws_i    = (int*)(xpair + (size_t)N_NODES * IN_DIM);
    int* counts  = ws_i;
    int* ovf_cnt = ws_i + N_NODES;
    int* ovf     = ws_i + N_NODES + 1;
    int* bucket  = ws_i + N_NODES + 1 + N_EDGES;

    hipMemsetAsync(counts, 0, (size_t)(N_NODES + 1) * sizeof(int), stream); // counts + ovf_cnt

    bucket_sh_mlp<<<EDGE_BLOCKS + MLP_BLOCKS, 256, 0, stream>>>(
        pos, ei, x, Wpre, bpre, Wpost, bpost, Wsc, bsc,
        counts, ovf_cnt, ovf, bucket, shbuf, xpair, out);

    node_gather<<<(N_NODES * 64) / 256, 256, 0, stream>>>(   // exactly 5000 blocks
        x, pos, ei, counts, bucket, (const _Float16*)shbuf, xpair, ovf_cnt, ovf, out);
}